// Round 2
// baseline (112.683 us; speedup 1.0000x reference)
//
#include <hip/hip_runtime.h>

#define BB 128
#define NN 128
#define EE 32

// ws layout in 4-byte elements:
// hx   : [HX_OFF,  HX_OFF + 16384*32)   f32
// hy   : [HY_OFF,  HY_OFF + 16384*32)   f32
// iso  : [ISO_OFF, ISO_OFF + 16384)     f32
// sat  : [SAT_OFF, SAT_OFF + 128)       f32-as-int (atomicMin)
// cnt  : [CNT_OFF]                      int
// total ~4.3 MB of d_ws
#define HX_OFF  0
#define HY_OFF  (16384 * 32)
#define ISO_OFF (2 * 16384 * 32)
#define SAT_OFF (ISO_OFF + 16384)
#define CNT_OFF (SAT_OFF + 128)

// ---------------------------------------------------------------------------
// Encode: per item (b,n) compute enc(32), isobj, hx(32), hy(32).
// 32 lanes per item (lane = output neuron e), 8 items per 256-thread block.
// ---------------------------------------------------------------------------
__global__ __launch_bounds__(256) void encode_kernel(
    const float* __restrict__ boxes, const int* __restrict__ classes,
    const float* __restrict__ scores,
    const float* __restrict__ W1, const float* __restrict__ b1,
    const float* __restrict__ W2, const float* __restrict__ b2,
    const float* __restrict__ Wo1, const float* __restrict__ bo1,
    const float* __restrict__ Wo2, const float* __restrict__ bo2,
    const float* __restrict__ Ws1, float* __restrict__ ws)
{
    const int t = threadIdx.x;

    // one-time init of sat[] / counter (pairs kernel is a later dispatch)
    if (blockIdx.x == 0) {
        if (t < 128) ((int*)ws)[SAT_OFF + t] = 0x3F800000; // 1.0f
        if (t == 128) ((int*)ws)[CNT_OFF] = 0;
    }

    const int item = blockIdx.x * 8 + (t >> 5);   // 0..16383  (= b*128+n)
    const int e = t & 31;

    // features: [x0,y0,x1,y1, class, score]
    const float* bx = boxes + item * 4;
    const float c0 = bx[0];
    const float c1 = bx[1];
    const float c2 = bx[2];
    const float c3 = bx[3];
    const float c4 = (float)classes[item];
    const float c5 = scores[item];

    // layer 1: h1 = relu(c @ W1 + b1)
    float h1 = b1[e];
    h1 = fmaf(c0, W1[0 * 32 + e], h1);
    h1 = fmaf(c1, W1[1 * 32 + e], h1);
    h1 = fmaf(c2, W1[2 * 32 + e], h1);
    h1 = fmaf(c3, W1[3 * 32 + e], h1);
    h1 = fmaf(c4, W1[4 * 32 + e], h1);
    h1 = fmaf(c5, W1[5 * 32 + e], h1);
    h1 = fmaxf(h1, 0.f);

    // layer 2: enc = h1 @ W2 + b2   (no relu on enc)
    float enc = b2[e];
#pragma unroll
    for (int k = 0; k < 32; k++) {
        enc = fmaf(__shfl(h1, k, 32), W2[k * 32 + e], enc);
    }

    // heads: u = relu(enc@Wo1+bo1), hx = enc@Ws1[:32], hy = enc@Ws1[32:]
    float u = bo1[e];
    float hx = 0.f, hy = 0.f;
#pragma unroll
    for (int k = 0; k < 32; k++) {
        const float ek = __shfl(enc, k, 32);
        u  = fmaf(ek, Wo1[k * 32 + e], u);
        hx = fmaf(ek, Ws1[k * 32 + e], hx);
        hy = fmaf(ek, Ws1[(32 + k) * 32 + e], hy);
    }
    u = fmaxf(u, 0.f);

    // isobj = sigmoid(u @ Wo2 + bo2)  -- reduce 32 lanes
    float v = u * Wo2[e];
#pragma unroll
    for (int off = 16; off >= 1; off >>= 1) v += __shfl_xor(v, off, 32);

    ws[HX_OFF + item * 32 + e] = hx;
    ws[HY_OFF + item * 32 + e] = hy;
    if (e == 0) {
        const float z = v + bo2[0];
        ws[ISO_OFF + item] = 1.f / (1.f + __expf(-z));
    }
}

// ---------------------------------------------------------------------------
// Pairs: per (b, i) compute exists_i = (1/denom) * sum_{j<nb} min(iso_j,
//   sigmoid(sum_k relu(hx_ik + hy_jk + bs1_k) * Ws2_k + bs2)),
// outer_i = max(1-iso_i, exists_i); sat_b = min over masked i; then mean.
// Grid: 128 b * 4 i-quarters. Block 256: 32 i's * 8 j-lanes.
// ---------------------------------------------------------------------------
__global__ __launch_bounds__(256) void pairs_kernel(
    const float* __restrict__ bs1, const float* __restrict__ Ws2,
    const float* __restrict__ bs2, const int* __restrict__ num_objects,
    float* __restrict__ ws, float* __restrict__ out, int nblocks)
{
    __shared__ float hyS[128 * 36];   // row stride 36: conflict-free + 16B aligned
    __shared__ float isoS[128];
    __shared__ float wred[4];
    __shared__ int lastFlag;
    __shared__ float r1[4], r2[4];

    const int t = threadIdx.x;
    const int b = blockIdx.x >> 2;
    const int q = blockIdx.x & 3;

    // stage hy tile + isobj
    const float* hyg = ws + HY_OFF + b * 128 * 32;
#pragma unroll
    for (int it = 0; it < 16; it++) {
        const int idx = t + it * 256;          // 0..4095
        hyS[(idx >> 5) * 36 + (idx & 31)] = hyg[idx];
    }
    if (t < 128) isoS[t] = ws[ISO_OFF + b * 128 + t];
    __syncthreads();

    const int nb = num_objects[b];
    const int i = q * 32 + (t >> 3);
    const int s = t & 7;

    float hxb[32];
    const float* hxg = ws + HX_OFF + (b * 128 + i) * 32;
#pragma unroll
    for (int k = 0; k < 32; k++) hxb[k] = hxg[k] + bs1[k];
    float w2[32];
#pragma unroll
    for (int k = 0; k < 32; k++) w2[k] = Ws2[k];
    const float bb = bs2[0];

    float acc = 0.f;
    for (int j = s; j < nb; j += 8) {
        const float* hr = hyS + j * 36;
        float d = bb;
#pragma unroll
        for (int k = 0; k < 32; k++) {
            d = fmaf(fmaxf(hxb[k] + hr[k], 0.f), w2[k], d);
        }
        const float same = 1.f / (1.f + __expf(-d));
        acc += fminf(isoS[j], same);
    }
    // sum the 8 j-lanes of this i
    acc += __shfl_xor(acc, 1);
    acc += __shfl_xor(acc, 2);
    acc += __shfl_xor(acc, 4);

    const float exists = acc / (float)(nb > 1 ? nb : 1);
    const float outer = fmaxf(1.f - isoS[i], exists);
    float val = (i < nb) ? outer : 1.f;

    // min over the 8 i's in this wave (lanes of same i hold identical val)
    val = fminf(val, __shfl_xor(val, 8));
    val = fminf(val, __shfl_xor(val, 16));
    val = fminf(val, __shfl_xor(val, 32));
    if ((t & 63) == 0) wred[t >> 6] = val;
    __syncthreads();

    if (t == 0) {
        const float m = fminf(fminf(wred[0], wred[1]), fminf(wred[2], wred[3]));
        atomicMin((int*)ws + SAT_OFF + b, __float_as_int(m)); // all vals > 0
        __threadfence();
        const int old = __hip_atomic_fetch_add((int*)ws + CNT_OFF, 1,
                                               __ATOMIC_ACQ_REL, __HIP_MEMORY_SCOPE_AGENT);
        lastFlag = (old == nblocks - 1) ? 1 : 0;
    }
    __syncthreads();

    if (lastFlag) {
        float contrib = 0.f, vcnt = 0.f;
        if (t < 128) {
            const int nbt = num_objects[t];
            const int sbits = __hip_atomic_load((int*)ws + SAT_OFF + t,
                                                __ATOMIC_RELAXED, __HIP_MEMORY_SCOPE_AGENT);
            const float sat = __int_as_float(sbits);
            const float valid = (nbt > 0) ? 1.f : 0.f;
            contrib = sat * valid;
            vcnt = valid;
        }
#pragma unroll
        for (int off = 1; off < 64; off <<= 1) {
            contrib += __shfl_xor(contrib, off);
            vcnt += __shfl_xor(vcnt, off);
        }
        if ((t & 63) == 0) { r1[t >> 6] = contrib; r2[t >> 6] = vcnt; }
        __syncthreads();
        if (t == 0) {
            const float sc = r1[0] + r1[1] + r1[2] + r1[3];
            const float cn = r2[0] + r2[1] + r2[2] + r2[3];
            out[0] = (cn > 0.f) ? (sc / cn) : 1.f;
        }
    }
}

extern "C" void kernel_launch(void* const* d_in, const int* in_sizes, int n_in,
                              void* d_out, int out_size, void* d_ws, size_t ws_size,
                              hipStream_t stream)
{
    const float* boxes       = (const float*)d_in[0];
    const int*   classes     = (const int*)d_in[1];
    const float* scores      = (const float*)d_in[2];
    const int*   num_objects = (const int*)d_in[3];
    const float* W1  = (const float*)d_in[4];
    const float* b1  = (const float*)d_in[5];
    const float* W2  = (const float*)d_in[6];
    const float* b2  = (const float*)d_in[7];
    const float* Wo1 = (const float*)d_in[8];
    const float* bo1 = (const float*)d_in[9];
    const float* Wo2 = (const float*)d_in[10];
    const float* bo2 = (const float*)d_in[11];
    const float* Ws1 = (const float*)d_in[12];
    const float* bs1 = (const float*)d_in[13];
    const float* Ws2 = (const float*)d_in[14];
    const float* bs2 = (const float*)d_in[15];

    float* ws  = (float*)d_ws;
    float* out = (float*)d_out;

    encode_kernel<<<2048, 256, 0, stream>>>(boxes, classes, scores,
                                            W1, b1, W2, b2, Wo1, bo1, Wo2, bo2,
                                            Ws1, ws);
    const int nblocks = 128 * 4;
    pairs_kernel<<<nblocks, 256, 0, stream>>>(bs1, Ws2, bs2, num_objects,
                                              ws, out, nblocks);
}